// Round 9
// baseline (175.215 us; speedup 1.0000x reference)
//
#include <hip/hip_runtime.h>

// MultiheadAttentionWithBias: B=2, L=2048, D=1024, H=16, HD=64
// cvt_all -> QKV GEMM (V^T fused epilogue) -> flash attn (32x32 MFMA,
// swapped QK^T, fixed-max softmax, in-register P via cvt_pk+permlane32_swap,
// dbuf LDS K/V, single barrier, counted vmcnt, XCD swizzle) -> out GEMM.
// R9: attn core rewritten to the 32x32 in-register structure.

typedef __attribute__((ext_vector_type(8))) short bf16x8;
typedef __attribute__((ext_vector_type(4))) float f32x4;
typedef __attribute__((ext_vector_type(16))) float f32x16;
typedef __attribute__((ext_vector_type(8))) unsigned short u16x8;
using u16 = unsigned short;

#define MFMA16(a, b, c) __builtin_amdgcn_mfma_f32_16x16x32_bf16((a), (b), (c), 0, 0, 0)
#define MFMA32(a, b, c) __builtin_amdgcn_mfma_f32_32x32x16_bf16((a), (b), (c), 0, 0, 0)
#define LOG2E 1.44269504088896f
#define QSCALE (0.125f * 1.44269504088896f)

__device__ __forceinline__ u16 f2bf(float f) {
  union { float f; unsigned int u; } v; v.f = f;
  unsigned int r = v.u + 0x7FFFu + ((v.u >> 16) & 1u);
  return (u16)(r >> 16);
}

__device__ __forceinline__ unsigned cvt_pk_bf16(float lo, float hi) {
  unsigned r;
  asm volatile("v_cvt_pk_bf16_f32 %0, %1, %2" : "=v"(r) : "v"(lo), "v"(hi));
  return r;
}

// Exchange: a' = {a.lanes0-31, b.lanes0-31}; b' = {a.lanes32-63, b.lanes32-63}
__device__ __forceinline__ void pl32swap(unsigned& a, unsigned& b) {
#if __has_builtin(__builtin_amdgcn_permlane32_swap)
  typedef unsigned pl2 __attribute__((ext_vector_type(2)));
  pl2 r = __builtin_amdgcn_permlane32_swap(a, b, false, false);
  a = r[0];
  b = r[1];
#else
  asm volatile("v_permlane32_swap_b32 %0, %1" : "+v"(a), "+v"(b));
#endif
}

__device__ __forceinline__ void g2lds16(const void* gsrc, void* ldst) {
  __builtin_amdgcn_global_load_lds(
      (const __attribute__((address_space(1))) unsigned int*)gsrc,
      (__attribute__((address_space(3))) unsigned int*)ldst, 16, 0, 0);
}

// ---------------- merged f32 -> bf16 convert (x, Wq, Wk, Wv, Wo) ----------------
__global__ __launch_bounds__(256) void cvt_all(
    const float* __restrict__ x, const float* __restrict__ wq,
    const float* __restrict__ wk, const float* __restrict__ wv,
    const float* __restrict__ wo, u16* __restrict__ xb,
    u16* __restrict__ w1b, u16* __restrict__ wob) {
  int bid = blockIdx.x, tid = threadIdx.x;
  const float* src; u16* dst; int i;
  if (bid < 2048)      { src = x;  dst = xb;            i = bid * 256 + tid; }
  else if (bid < 2560) { src = wq; dst = w1b;           i = (bid - 2048) * 256 + tid; }
  else if (bid < 3072) { src = wk; dst = w1b + (1<<20); i = (bid - 2560) * 256 + tid; }
  else if (bid < 3584) { src = wv; dst = w1b + (2<<20); i = (bid - 3072) * 256 + tid; }
  else                 { src = wo; dst = wob;           i = (bid - 3584) * 256 + tid; }
  const float4* s = (const float4*)src;
  float4 a = s[2 * i], b = s[2 * i + 1];
  u16x8 o;
  o[0] = f2bf(a.x); o[1] = f2bf(a.y); o[2] = f2bf(a.z); o[3] = f2bf(a.w);
  o[4] = f2bf(b.x); o[5] = f2bf(b.y); o[6] = f2bf(b.z); o[7] = f2bf(b.w);
  ((u16x8*)dst)[i] = o;
}

// ---------------- GEMM C = A * B^T (unchanged, passing) ----------------
template <int MODE>
__global__ __launch_bounds__(256, 2) void gemm_bt(
    const u16* __restrict__ A, const u16* __restrict__ B,
    u16* __restrict__ qp, u16* __restrict__ kp, u16* __restrict__ vp,
    const float* __restrict__ b0, const float* __restrict__ b1,
    const float* __restrict__ b2, float* __restrict__ outp,
    const float* __restrict__ bo) {
  __shared__ __align__(16) u16 lA[128 * 64];
  __shared__ __align__(16) u16 lB[128 * 64];
  const int tid = threadIdx.x;
  const int lane = tid & 63, wid = tid >> 6;
  const int g = lane >> 4, cc = lane & 15;
  const int wr = wid >> 1, wc = wid & 1;
  const int m0 = blockIdx.y * 128, n0 = blockIdx.x * 128;
  f32x4 acc[4][4] = {};
  for (int kt = 0; kt < 16; ++kt) {
    const int kof = kt * 64;
#pragma unroll
    for (int i = 0; i < 4; ++i) {
      int cid = i * 256 + tid;
      int row = cid >> 3;
      int col = (cid & 7) * 8;
      g2lds16(A + (size_t)(m0 + row) * 1024 + kof + col, &lA[(i * 256 + wid * 64) * 8]);
      g2lds16(B + (size_t)(n0 + row) * 1024 + kof + col, &lB[(i * 256 + wid * 64) * 8]);
    }
    __syncthreads();
#pragma unroll
    for (int kc = 0; kc < 2; ++kc) {
      bf16x8 af[4], bfr[4];
#pragma unroll
      for (int mf = 0; mf < 4; ++mf)
        af[mf] = *(const bf16x8*)&lA[(wr * 64 + mf * 16 + cc) * 64 + kc * 32 + g * 8];
#pragma unroll
      for (int nf = 0; nf < 4; ++nf)
        bfr[nf] = *(const bf16x8*)&lB[(wc * 64 + nf * 16 + cc) * 64 + kc * 32 + g * 8];
#pragma unroll
      for (int mf = 0; mf < 4; ++mf)
#pragma unroll
        for (int nf = 0; nf < 4; ++nf)
          acc[mf][nf] = MFMA16(af[mf], bfr[nf], acc[mf][nf]);
    }
    __syncthreads();
  }
#pragma unroll
  for (int mf = 0; mf < 4; ++mf) {
#pragma unroll
    for (int nf = 0; nf < 4; ++nf) {
      int n = n0 + wc * 64 + nf * 16 + cc;
      if (MODE == 0) {
        int which = n >> 10;
        int nn = n & 1023;
        const float* bp = which == 0 ? b0 : (which == 1 ? b1 : b2);
        float bias = bp[nn];
        int h = nn >> 6, hd = nn & 63;
        int mb = m0 + wr * 64 + mf * 16 + g * 4;
        int bb = mb >> 11, ll0 = mb & 2047;
        if (which == 2) {
          ushort4 pk4;
          pk4.x = f2bf(acc[mf][nf][0] + bias);
          pk4.y = f2bf(acc[mf][nf][1] + bias);
          pk4.z = f2bf(acc[mf][nf][2] + bias);
          pk4.w = f2bf(acc[mf][nf][3] + bias);
          *(ushort4*)&vp[(((size_t)(bb * 16 + h)) * 64 + hd) * 2048 + ll0] = pk4;
        } else {
          u16* dp = which == 0 ? qp : kp;
#pragma unroll
          for (int r = 0; r < 4; ++r) {
            float val = acc[mf][nf][r] + bias;
            if (which == 0) val *= QSCALE;
            dp[(((size_t)(bb * 16 + h)) * 2048 + ll0 + r) * 64 + hd] = f2bf(val);
          }
        }
      } else {
        float bias = bo[n];
#pragma unroll
        for (int r = 0; r < 4; ++r) {
          int m = m0 + wr * 64 + mf * 16 + g * 4 + r;
          outp[(size_t)m * 1024 + n] = acc[mf][nf][r] + bias;
        }
      }
    }
  }
}

// ---------------- Flash attention: 32x32 MFMA, fixed-max, in-register P -------
// Block = 4 waves (256 thr), ONE (batch, head, 128-q-row strip); wave owns 32 q.
// Swapped S^T = mfma32(K, Q): lane holds q = lane&31, k = (r&3)+8(r>>2)+4*hi.
// Fixed max M=32 (log2-domain) folded into MFMA acc init (-32): P = 2^(s-32).
// Constant cancels in P/sum(P) exactly; s <= ~14 whp so P in [2^-60, 2^-18]:
// safe in bf16/f32. No max tracking, no rescale, no cross-lane reduce in loop;
// lsum per-lane (own 16 k's), one shfl_xor(32) at the end.
// P -> PA fragments: cvt_pk_bf16 pairs + permlane32_swap (verified layout).
// Schedule (R8 template): stage K,V(t+1)->buf^1; compute(t); issue bias(t+2);
// vmcnt(8) drains stage; ONE barrier.
__global__ __launch_bounds__(256, 2) void attn_kernel(
    const u16* __restrict__ qm, const u16* __restrict__ km,
    const u16* __restrict__ vtm, const float* __restrict__ bias,
    u16* __restrict__ aout) {
  __shared__ __align__(16) u16 lK[2][4096];   // dbuf 64k x 64d bf16: 16KB
  __shared__ __align__(16) u16 lV[2][4096];   // dbuf 64d x 64k bf16 (V^T): 16KB
  const int tid = threadIdx.x;
  const int lane = tid & 63, wid = tid >> 6;
  const int lq = lane & 31, hi = lane >> 5;
  // XCD swizzle: 512 blocks; xcd = lin&7 owns heads 2*xcd, 2*xcd+1
  const int lin = blockIdx.x;
  const int xcd = lin & 7, j = lin >> 3;      // j in [0,64)
  const int h = xcd * 2 + (j >> 5);
  const int rem = j & 31;
  const int b = rem >> 4, qb = rem & 15;
  const int q0w = qb * 128 + wid * 32;
  const size_t bh = (size_t)b * 16 + h;
  const u16* kg = km + bh * 2048 * 64;
  const u16* vg = vtm + bh * 64 * 2048;
  const u16* qbase = qm + (bh * 2048 + q0w) * 64;
  // lane's q-row bias base (+4*hi: this half's k-offset)
  const float* brow = bias + ((size_t)h * 2048 + q0w + lq) * 2048 + 4 * hi;

  // Q fragments (B-operand), constant across iterations: Q[q=lq][d=i*16+8hi..]
  bf16x8 qf[4];
#pragma unroll
  for (int i = 0; i < 4; ++i)
    qf[i] = *(const bf16x8*)&qbase[(size_t)lq * 64 + i * 16 + 8 * hi];

  f32x16 o[2];
#pragma unroll
  for (int r = 0; r < 16; ++r) { o[0][r] = 0.f; o[1][r] = 0.f; }
  float lsum = 0.f;

  // stage one 64x64 tile (256 thr x 2 g2lds), pre-swizzled source chunk^=row&7
#define STAGE_TILE(gbase, rs, ldst)                                            \
  _Pragma("unroll") for (int rep = 0; rep < 2; ++rep) {                        \
    int i = rep * 256 + tid;                                                   \
    int row = i >> 3, pcol = i & 7;                                            \
    int lcol = pcol ^ (row & 7);                                               \
    g2lds16((gbase) + (size_t)row * (rs) + lcol * 8, (ldst) + i * 8);          \
  }

  // one 32-k subtile: QK^T (acc init -32) + bias + exp2 + pack/swap + PV
#define SUBTILE(s_, BC, PP)                                                    \
  {                                                                            \
    f32x16 acc;                                                                \
    _Pragma("unroll") for (int r = 0; r < 16; ++r) acc[r] = -32.0f;            \
    _Pragma("unroll") for (int i = 0; i < 4; ++i) {                            \
      int row = (s_) * 32 + lq;                                                \
      bf16x8 kf = *(const bf16x8*)&lK[PP][row * 64 + (((2 * i + hi) ^ (row & 7))) * 8]; \
      acc = MFMA32(kf, qf[i], acc);                                            \
    }                                                                          \
    _Pragma("unroll") for (int r = 0; r < 16; ++r)                             \
      acc[r] = fmaf(BC[(s_) * 4 + (r >> 2)][r & 3], LOG2E, acc[r]);            \
    float p[16];                                                               \
    _Pragma("unroll") for (int r = 0; r < 16; ++r) {                           \
      p[r] = __builtin_amdgcn_exp2f(acc[r]);                                   \
      lsum += p[r];                                                            \
    }                                                                          \
    unsigned c0 = cvt_pk_bf16(p[0], p[1]),   c1 = cvt_pk_bf16(p[2], p[3]);     \
    unsigned c2 = cvt_pk_bf16(p[4], p[5]),   c3 = cvt_pk_bf16(p[6], p[7]);     \
    unsigned c4 = cvt_pk_bf16(p[8], p[9]),   c5 = cvt_pk_bf16(p[10], p[11]);   \
    unsigned c6 = cvt_pk_bf16(p[12], p[13]), c7 = cvt_pk_bf16(p[14], p[15]);   \
    pl32swap(c0, c2); pl32swap(c1, c3);  /* A_k0..15 dwords */                 \
    pl32swap(c4, c6); pl32swap(c5, c7);  /* A_k16..31 dwords */                \
    union { unsigned u[4]; bf16x8 v; } a0, a1;                                 \
    a0.u[0] = c0; a0.u[1] = c1; a0.u[2] = c2; a0.u[3] = c3;                    \
    a1.u[0] = c4; a1.u[1] = c5; a1.u[2] = c6; a1.u[3] = c7;                    \
    _Pragma("unroll") for (int dblk = 0; dblk < 2; ++dblk) {                   \
      int rowv = dblk * 32 + lq;                                               \
      bf16x8 v0 = *(const bf16x8*)&lV[PP][rowv * 64 + (((4 * (s_) + hi) ^ (rowv & 7))) * 8];     \
      bf16x8 v1 = *(const bf16x8*)&lV[PP][rowv * 64 + (((4 * (s_) + 2 + hi) ^ (rowv & 7))) * 8]; \
      o[dblk] = MFMA32(a0.v, v0, o[dblk]);                                     \
      o[dblk] = MFMA32(a1.v, v1, o[dblk]);                                     \
    }                                                                          \
  }

  float4 bA[8], bB[8];
  // prologue: stage K/V(0) -> buf0 (oldest 4), bias(0)->bA, bias(1)->bB
  STAGE_TILE(kg, 64, (u16*)lK[0])
  STAGE_TILE(vg, 2048, (u16*)lV[0])
  __builtin_amdgcn_sched_barrier(0);
#pragma unroll
  for (int gi = 0; gi < 8; ++gi) {
    bA[gi] = *(const float4*)(brow + (gi >> 2) * 32 + (gi & 3) * 8);
    bB[gi] = *(const float4*)(brow + 64 + (gi >> 2) * 32 + (gi & 3) * 8);
  }
  __builtin_amdgcn_sched_barrier(0);
  asm volatile("s_waitcnt vmcnt(8)" ::: "memory");  // K/V(0)+bias(0) landed
  __builtin_amdgcn_sched_barrier(0);
  __builtin_amdgcn_s_barrier();
  __builtin_amdgcn_sched_barrier(0);

#define ATTN_STEP(kt_, BC, DOSTAGE, DOBIAS)                                    \
  {                                                                            \
    const int k0 = (kt_) * 64;                                                 \
    const int PP = (kt_) & 1;                                                  \
    if (DOSTAGE) {                                                             \
      STAGE_TILE(kg + (size_t)(k0 + 64) * 64, 64, (u16*)lK[PP ^ 1])            \
      STAGE_TILE(vg + (k0 + 64), 2048, (u16*)lV[PP ^ 1])                       \
    }                                                                          \
    __builtin_amdgcn_sched_barrier(0);                                         \
    SUBTILE(0, BC, PP)                                                         \
    SUBTILE(1, BC, PP)                                                         \
    /* refill BC with bias(t+2) (~1.8 iters of flight) */                      \
    if (DOBIAS) {                                                              \
      _Pragma("unroll") for (int gi = 0; gi < 8; ++gi)                         \
          BC[gi] = *(const float4*)(brow + k0 + 128 + (gi >> 2) * 32 + (gi & 3) * 8); \
    }                                                                          \
    __builtin_amdgcn_sched_barrier(0);                                         \
    if (DOSTAGE && DOBIAS) { asm volatile("s_waitcnt vmcnt(8)" ::: "memory"); }\
    else                   { asm volatile("s_waitcnt vmcnt(0)" ::: "memory"); }\
    __builtin_amdgcn_sched_barrier(0);                                         \
    if (DOSTAGE) { __builtin_amdgcn_s_barrier(); }                             \
    __builtin_amdgcn_sched_barrier(0);                                         \
  }

#pragma unroll 1
  for (int kt = 0; kt < 30; kt += 2) {
    ATTN_STEP(kt, bA, 1, 1)
    ATTN_STEP(kt + 1, bB, 1, 1)
  }
  ATTN_STEP(30, bA, 1, 0)
  ATTN_STEP(31, bB, 0, 0)
#undef ATTN_STEP
#undef SUBTILE
#undef STAGE_TILE

  // finalize: complete row sums across halves, normalize, write bf16
  lsum += __shfl_xor(lsum, 32, 64);
  float linv = 1.0f / lsum;
#pragma unroll
  for (int r = 0; r < 16; ++r) {
    int qr = (r & 3) + 8 * (r >> 2) + 4 * hi;
    float lr = __shfl(linv, qr, 64);  // lane qr holds linv for q-row qr
    size_t base = ((size_t)b * 2048 + q0w + qr) * 1024 + h * 64 + lq;
    aout[base] = f2bf(o[0][r] * lr);
    aout[base + 32] = f2bf(o[1][r] * lr);
  }
}

extern "C" void kernel_launch(void* const* d_in, const int* in_sizes, int n_in,
                              void* d_out, int out_size, void* d_ws, size_t ws_size,
                              hipStream_t stream) {
  const float* x  = (const float*)d_in[0];
  const float* rb = (const float*)d_in[1];
  const float* Wq = (const float*)d_in[2];
  const float* bq = (const float*)d_in[3];
  const float* Wk = (const float*)d_in[4];
  const float* bk = (const float*)d_in[5];
  const float* Wv = (const float*)d_in[6];
  const float* bv = (const float*)d_in[7];
  const float* Wo = (const float*)d_in[8];
  const float* bo = (const float*)d_in[9];
  float* out = (float*)d_out;
  char* ws = (char*)d_ws;

  u16* xb   = (u16*)(ws);                 // 8 MB  [4096,1024] bf16 (reused as aout)
  u16* W1b  = (u16*)(ws + (8 << 20));     // 6 MB  [3072,1024] bf16 (Wq|Wk|Wv)
  u16* Wob  = (u16*)(ws + (14 << 20));    // 2 MB  [1024,1024] bf16
  u16* qb   = (u16*)(ws + (16 << 20));    // 8 MB  [B,H,L,HD]
  u16* kb2  = (u16*)(ws + (24 << 20));    // 8 MB  [B,H,L,HD]
  u16* vtb  = (u16*)(ws + (32 << 20));    // 8 MB  [B,H,HD,L] (written by QKV GEMM)
  u16* aout = xb;                         // alias: xb dead after QKV GEMM

  cvt_all<<<4096, 256, 0, stream>>>(x, Wq, Wk, Wv, Wo, xb, W1b, Wob);
  gemm_bt<0><<<dim3(24, 32), 256, 0, stream>>>(xb, W1b, qb, kb2, vtb, bq, bk, bv,
                                               nullptr, nullptr);
  attn_kernel<<<512, 256, 0, stream>>>(qb, kb2, vtb, rb, aout);
  gemm_bt<1><<<dim3(8, 32), 256, 0, stream>>>(aout, Wob, nullptr, nullptr, nullptr,
                                              nullptr, nullptr, nullptr, out, bo);
}